// Round 8
// baseline (172.199 us; speedup 1.0000x reference)
//
#include <hip/hip_runtime.h>
#include <math.h>

// Problem constants (B,N,D)=(8,2048,256), S=128, H=512, E=2H+S=1152
#define BB 8
#define NN 2048
#define DD 256
#define SS 128
#define HH 512
#define EE 1152

typedef short bf16x8 __attribute__((ext_vector_type(8)));
typedef float f32x4 __attribute__((ext_vector_type(4)));

__device__ __forceinline__ short f2bf(float f) {
    union { float f; unsigned u; } a; a.f = f;
    unsigned r = a.u + 0x7FFFu + ((a.u >> 16) & 1u);  // RNE
    return (short)(r >> 16);
}
__device__ __forceinline__ float bf2f(short s) {
    union { unsigned u; float f; } a; a.u = ((unsigned)(unsigned short)s) << 16;
    return a.f;
}

// ---------------- K1: fused RMS norm + weight prep (one launch) ------------
// blocks [0,4096): rmsnorm x->xn bf16 (4 rows/block, wave-per-row)
// blocks [4096,4384): Wuv (DxE) -> Wuv_t (ExD) bf16, 32x32 LDS tiles
// blocks [4384,4512): Wo (HxD) -> Wo_t (DxH) bf16, 32x32 LDS tiles
__global__ __launch_bounds__(256) void k_pre(
        const float* __restrict__ x, const float* __restrict__ gp,
        short* __restrict__ xn,
        const float* __restrict__ Wuv, const float* __restrict__ Wo,
        short* __restrict__ Wuv_t, short* __restrict__ Wo_t) {
    __shared__ float tile[32][33];
    int bid = blockIdx.x;
    int t = threadIdx.x;
    if (bid < 4096) {
        int wave = t >> 6, lane = t & 63;
        long row = (long)bid * 4 + wave;
        float4 xv = ((const float4*)(x + row * DD))[lane];
        float ss = xv.x*xv.x + xv.y*xv.y + xv.z*xv.z + xv.w*xv.w;
        #pragma unroll
        for (int off = 32; off > 0; off >>= 1) ss += __shfl_down(ss, off);
        ss = __shfl(ss, 0);
        float norm = sqrtf(ss) * 0.0625f;              // ||x|| / sqrt(256)
        float scale = gp[0] / fmaxf(norm, 1e-5f);
        short4 o;
        o.x = f2bf(xv.x * scale); o.y = f2bf(xv.y * scale);
        o.z = f2bf(xv.z * scale); o.w = f2bf(xv.w * scale);
        ((short4*)(xn + row * DD))[lane] = o;
    } else if (bid < 4384) {
        int bid2 = bid - 4096;                // 36 e-tiles x 8 d-tiles
        int et = bid2 % 36, dt = bid2 / 36;
        #pragma unroll
        for (int i = 0; i < 4; i++) {
            int idx = t + i*256, r = idx >> 5, c = idx & 31;
            tile[r][c] = Wuv[(long)(dt*32 + r)*EE + et*32 + c];
        }
        __syncthreads();
        #pragma unroll
        for (int i = 0; i < 4; i++) {
            int idx = t + i*256, r = idx >> 5, c = idx & 31;
            Wuv_t[(long)(et*32 + r)*DD + dt*32 + c] = f2bf(tile[c][r]);
        }
    } else {
        int bid3 = bid - 4384;                // 16 h-tiles x 8 d-tiles
        int ht = bid3 % 16, dt = bid3 / 16;
        #pragma unroll
        for (int i = 0; i < 4; i++) {
            int idx = t + i*256, r = idx >> 5, c = idx & 31;
            tile[r][c] = Wo[(long)(ht*32 + r)*DD + dt*32 + c];
        }
        __syncthreads();
        #pragma unroll
        for (int i = 0; i < 4; i++) {
            int idx = t + i*256, r = idx >> 5, c = idx & 31;
            Wo_t[(long)(dt*32 + r)*HH + ht*32 + c] = f2bf(tile[c][r]);
        }
    }
}

// ---------------- K3: GEMM1 + silu + split epilogue (v8) -------------------
// 128x128 tile, 4 waves, 4x4 acc/wave. Register-prefetch staging: tile ki+1
// loaded into VGPRs POST-barrier (ages ~compute-phase before its ds_write
// waitcnt), replacing gl_lds16 whose loads were drained cold at the barrier.
// __launch_bounds__(256,3): 3 blocks/CU for cross-block drain overlap.
// v-epilogue writes vfrag B-frag layout directly (proven r7).
__global__ __launch_bounds__(256, 3) void k_gemm1(
        const short* __restrict__ xn, const short* __restrict__ Wuv_t,
        const float* __restrict__ b_uv,
        const float* __restrict__ gamma, const float* __restrict__ beta,
        short* __restrict__ u, short* __restrict__ vfrag,
        short* __restrict__ q, short* __restrict__ k) {
    __shared__ short As[128*64];
    __shared__ short Bs[128*64];
    int m0 = blockIdx.x * 128, n0 = blockIdx.y * 128;
    int t = threadIdx.x, w = t >> 6, lane = t & 63;
    int wr = w & 1, wc = w >> 1, l16 = lane & 15, quad = lane >> 4;
    int srow = t >> 1, scol = (t & 1) * 32;   // staging: row, 32-short half
    f32x4 acc[4][4] = {};
    // prologue: load k0=0 tiles into regs
    bf16x8 aS[4], bS[4];
    #pragma unroll
    for (int j = 0; j < 4; j++) {
        aS[j] = *(const bf16x8*)&xn[(long)(m0 + srow)*DD + scol + j*8];
        bS[j] = *(const bf16x8*)&Wuv_t[(long)(n0 + srow)*DD + scol + j*8];
    }
    for (int ki = 0; ki < 4; ki++) {
        // write staged regs -> LDS (regs loaded >= 1 phase ago)
        #pragma unroll
        for (int j = 0; j < 4; j++) {
            *(bf16x8*)&As[srow*64 + scol + j*8] = aS[j];
            *(bf16x8*)&Bs[srow*64 + scol + j*8] = bS[j];
        }
        __syncthreads();                     // staging visible
        if (ki < 3) {                        // post-barrier prefetch of ki+1
            int k0 = (ki + 1) * 64;
            #pragma unroll
            for (int j = 0; j < 4; j++) {
                aS[j] = *(const bf16x8*)&xn[(long)(m0 + srow)*DD + k0 + scol + j*8];
                bS[j] = *(const bf16x8*)&Wuv_t[(long)(n0 + srow)*DD + k0 + scol + j*8];
            }
        }
        #pragma unroll
        for (int kk = 0; kk < 2; kk++) {
            bf16x8 a[4], bb[4];
            #pragma unroll
            for (int mt = 0; mt < 4; mt++)
                a[mt] = *(const bf16x8*)&As[(wr*64 + mt*16 + l16)*64 + kk*32 + quad*8];
            #pragma unroll
            for (int nt = 0; nt < 4; nt++)
                bb[nt] = *(const bf16x8*)&Bs[(wc*64 + nt*16 + l16)*64 + kk*32 + quad*8];
            #pragma unroll
            for (int mt = 0; mt < 4; mt++)
                #pragma unroll
                for (int nt = 0; nt < 4; nt++)
                    acc[mt][nt] = __builtin_amdgcn_mfma_f32_16x16x32_bf16(
                        a[mt], bb[nt], acc[mt][nt], 0,0,0);
        }
        __syncthreads();                     // compute reads done (WAR)
    }
    #pragma unroll
    for (int mt = 0; mt < 4; mt++)
    #pragma unroll
    for (int nt = 0; nt < 4; nt++) {
        int gm0 = m0 + wr*64 + mt*16 + quad*4;        // rows gm0..gm0+3
        int ge  = n0 + wc*64 + nt*16 + l16;
        float val[4];
        #pragma unroll
        for (int r = 0; r < 4; r++) {
            float xv = acc[mt][nt][r] + b_uv[ge];
            val[r] = xv / (1.0f + __expf(-xv));        // silu
        }
        if (ge < HH) {
            #pragma unroll
            for (int r = 0; r < 4; r++)
                u[(long)(gm0 + r)*HH + ge] = f2bf(val[r]);
        } else if (ge < 2*HH) {
            int h = ge - HH;
            // vfrag addr: ((b*64+mt32)*32 + ht)*512 + lane'*8 + e
            long base = (((long)((gm0 >> 11)*64 + ((gm0 & 2047) >> 5)) * 32)
                         + (h >> 4)) * 512
                        + ((((gm0 & 31) >> 3)*16 + (h & 15)) * 8) + (gm0 & 7);
            short4 o;
            o.x = f2bf(val[0]); o.y = f2bf(val[1]);
            o.z = f2bf(val[2]); o.w = f2bf(val[3]);
            *(short4*)&vfrag[base] = o;
        } else {
            int si = ge - 2*HH;
            #pragma unroll
            for (int r = 0; r < 4; r++) {
                q[(long)(gm0 + r)*SS + si] = f2bf(val[r] * gamma[si]      + beta[si]);
                k[(long)(gm0 + r)*SS + si] = f2bf(val[r] * gamma[SS + si] + beta[SS + si]);
            }
        }
    }
}

// ---------------- K5: attention + u-gate + fused GEMM2 (v8) ----------------
// Main loop unrolled x2 with alternating register sets (no reg copies).
// vf / k global loads issued POST-barrier -> age >=1 phase before any
// vmcnt(0) drain; barrier drain ~free. LDS hazard schedule identical to the
// proven v4 pattern (write->barrier->read / read->barrier->overwrite).
// Epilogue: race-proof r7 version (disjoint gtile halves, 2 barriers).
#define KS(p,row)  (smem + ((p)*32 + (row))*136)
#define PS(p,row)  (smem + 8704 + ((p)*64 + (row))*40)
#define GT(hf,row) (smem + (hf)*16896 + (row)*264)

__global__ __launch_bounds__(512, 2) void k_attn(
        const short* __restrict__ q, const short* __restrict__ k,
        const short* __restrict__ vfrag, const short* __restrict__ u,
        const short* __restrict__ Wo_t, const float* __restrict__ b_o,
        float* __restrict__ out) {
    extern __shared__ __align__(16) short smem[];
    int b = blockIdx.x & 7;                  // batch -> XCD pin
    int i0 = (blockIdx.x >> 3) * 64;
    int t = threadIdx.x, w = t >> 6, lane = t & 63;
    int l16 = lane & 15, quad = lane >> 4;
    int qt = w >> 1, mt = w & 1;             // QK tile assignment
    const short* qb  = q + ((long)b * NN + i0) * SS;
    const short* kb  = k + (long)b * NN * SS;
    const short* vfb = vfrag + (long)b * 64 * 32 * 512;
    const float RS = 0.08838834764831845f;   // 1/sqrt(128)

    int krow = t >> 4, kch = (t & 15) * 8;   // k staging map: 32 rows x 256B

    // hoist q B-frags for this wave's q-tile: B[n=q=l16][k=s]
    bf16x8 qf[4];
    #pragma unroll
    for (int kc = 0; kc < 4; kc++)
        qf[kc] = *(const bf16x8*)&qb[(long)(qt*16 + l16)*SS + kc*32 + quad*8];

    // prologue: ks[0] <- tile0; kregB = tile1; kregA = tile2; vfA = vf(tile0)
    *(bf16x8*)&KS(0,krow)[kch] = *(const bf16x8*)&kb[(long)krow*SS + kch];
    bf16x8 kregB = *(const bf16x8*)&kb[(long)(32 + krow)*SS + kch];
    bf16x8 kregA = *(const bf16x8*)&kb[(long)(64 + krow)*SS + kch];
    bf16x8 vfA[4], vfB[4];
    #pragma unroll
    for (int jj = 0; jj < 4; jj++)
        vfA[jj] = *(const bf16x8*)&vfb[((long)(w*4 + jj))*512 + lane*8];
    __syncthreads();                         // drains all prologue loads

    f32x4 acc[16] = {};
    for (int s = 0; s < 32; s++) {
        // ---------------- iter A: tile 2s, ks/Ps parity 0 ----------------
        {
            f32x4 sc = {};
            #pragma unroll
            for (int kc = 0; kc < 4; kc++) {
                bf16x8 kf = *(const bf16x8*)&KS(0, mt*16 + l16)[kc*32 + quad*8];
                sc = __builtin_amdgcn_mfma_f32_16x16x32_bf16(kf, qf[kc], sc, 0,0,0);
            }
            short4 pw;
            float s0 = fmaxf(sc[0]*RS, 0.f), s1 = fmaxf(sc[1]*RS, 0.f);
            float s2 = fmaxf(sc[2]*RS, 0.f), s3 = fmaxf(sc[3]*RS, 0.f);
            pw.x = f2bf(s0*s0); pw.y = f2bf(s1*s1);
            pw.z = f2bf(s2*s2); pw.w = f2bf(s3*s3);
            *(short4*)&PS(0, qt*16 + l16)[mt*16 + quad*4] = pw;
            *(bf16x8*)&KS(1, krow)[kch] = kregB;       // tile 2s+1 (aged >1 iter)
            __syncthreads();
            // post-barrier loads (age ~1 iter before next drain)
            int tk = (2*s + 3 < 64) ? 2*s + 3 : 63;
            kregB = *(const bf16x8*)&kb[(long)(tk*32 + krow)*SS + kch];
            #pragma unroll
            for (int jj = 0; jj < 4; jj++)
                vfB[jj] = *(const bf16x8*)&vfb[((long)(2*s+1)*32 + w*4 + jj)*512 + lane*8];
            bf16x8 af[4];
            #pragma unroll
            for (int qq2 = 0; qq2 < 4; qq2++)
                af[qq2] = *(const bf16x8*)&PS(0, qq2*16 + l16)[quad*8];
            #pragma unroll
            for (int jj = 0; jj < 4; jj++)
                #pragma unroll
                for (int qq2 = 0; qq2 < 4; qq2++)
                    acc[qq2*4 + jj] = __builtin_amdgcn_mfma_f32_16x16x32_bf16(
                        af[qq2], vfA[jj], acc[qq2*4 + jj], 0,0,0);
        }
        // ---------------- iter B: tile 2s+1, parity 1 --------------------
        {
            f32x4 sc = {};
            #pragma unroll
            for (int kc = 0; kc < 4; kc++) {
                bf16x8 kf = *(const bf16x8*)&KS(1, mt*16 + l16)[kc*32 + quad*8];
                sc = __builtin_amdgcn_mfma_f32_16x16x32_bf16(kf, qf[kc], sc, 0,0,0);
            }
            short4 pw;
            float s0 = fmaxf(sc[0]*RS, 0.f), s1 = fmaxf(sc[1]*RS, 0.f);
            float s2 = fmaxf(sc[2]*RS, 0.f), s3 = fmaxf(sc[3]*RS, 0.f);
            pw.x = f2bf(s0*s0); pw.y = f2bf(s1*s1);
            pw.z = f2bf(s2*s2); pw.w = f2bf(s3*s3);
            *(short4*)&PS(1, qt*16 + l16)[mt*16 + quad*4] = pw;
            *(bf16x8*)&KS(0, krow)[kch] = kregA;       // tile 2s+2
            __syncthreads();
            int tk = (2*s + 4 < 64) ? 2*s + 4 : 63;
            kregA = *(const bf16x8*)&kb[(long)(tk*32 + krow)*SS + kch];
            int tv = (2*s + 2 < 64) ? 2*s + 2 : 63;
            #pragma unroll
            for (int jj = 0; jj < 4; jj++)
                vfA[jj] = *(const bf16x8*)&vfb[((long)tv*32 + w*4 + jj)*512 + lane*8];
            bf16x8 af[4];
            #pragma unroll
            for (int qq2 = 0; qq2 < 4; qq2++)
                af[qq2] = *(const bf16x8*)&PS(1, qq2*16 + l16)[quad*8];
            #pragma unroll
            for (int jj = 0; jj < 4; jj++)
                #pragma unroll
                for (int qq2 = 0; qq2 < 4; qq2++)
                    acc[qq2*4 + jj] = __builtin_amdgcn_mfma_f32_16x16x32_bf16(
                        af[qq2], vfB[jj], acc[qq2*4 + jj], 0,0,0);
        }
    }

    // ---- fused GEMM2 epilogue: out[64 x 256] = (u .* PV) @ Wo + b_o ----
    // acc C-layout: q = qq2*16+quad*4+r, h = w*64 + jj*16 + l16.
    long rowbase = (long)b * NN + i0;
    __syncthreads();                         // B1: all main-loop LDS ops dead
    {
        int hf = w >> 2;                     // this wave's h-half buffer
        int hbase = (w & 3) * 64;            // col offset within half
        #pragma unroll
        for (int qq2 = 0; qq2 < 4; qq2++)
        #pragma unroll
        for (int jj = 0; jj < 4; jj++) {
            int gh = w*64 + jj*16 + l16;     // global h
            #pragma unroll
            for (int r = 0; r < 4; r++) {
                long grow = rowbase + qq2*16 + quad*4 + r;
                float uval = bf2f(u[grow*HH + gh]);
                GT(hf, qq2*16 + quad*4 + r)[hbase + jj*16 + l16] =
                    f2bf(acc[qq2*4 + jj][r] * uval);
            }
        }
    }
    __syncthreads();                         // B2: writes visible; reads only below
    f32x4 acc2[4][2] = {};
    #pragma unroll
    for (int p = 0; p < 2; p++) {            // h-halves, disjoint buffers
        #pragma unroll
        for (int kc = 0; kc < 8; kc++) {
            bf16x8 A[4], Bf[2];
            #pragma unroll
            for (int mt2 = 0; mt2 < 4; mt2++)
                A[mt2] = *(const bf16x8*)&GT(p, mt2*16 + l16)[kc*32 + quad*8];
            #pragma unroll
            for (int nt = 0; nt < 2; nt++)
                Bf[nt] = *(const bf16x8*)&Wo_t[(long)(w*32 + nt*16 + l16)*HH
                                               + p*256 + kc*32 + quad*8];
            #pragma unroll
            for (int mt2 = 0; mt2 < 4; mt2++)
                #pragma unroll
                for (int nt = 0; nt < 2; nt++)
                    acc2[mt2][nt] = __builtin_amdgcn_mfma_f32_16x16x32_bf16(
                        A[mt2], Bf[nt], acc2[mt2][nt], 0,0,0);
        }
    }
    // store out + bias (fp32)
    #pragma unroll
    for (int mt2 = 0; mt2 < 4; mt2++)
    #pragma unroll
    for (int nt = 0; nt < 2; nt++)
    #pragma unroll
    for (int r = 0; r < 4; r++) {
        long grow = rowbase + mt2*16 + quad*4 + r;
        int gd = w*32 + nt*16 + l16;
        out[grow*DD + gd] = acc2[mt2][nt][r] + b_o[gd];
    }
}

extern "C" void kernel_launch(void* const* d_in, const int* in_sizes, int n_in,
                              void* d_out, int out_size, void* d_ws, size_t ws_size,
                              hipStream_t stream) {
    const float* x     = (const float*)d_in[0];
    const float* g     = (const float*)d_in[1];
    const float* Wuv   = (const float*)d_in[2];
    const float* b_uv  = (const float*)d_in[3];
    const float* gamma = (const float*)d_in[4];
    const float* beta  = (const float*)d_in[5];
    const float* Wo    = (const float*)d_in[6];
    const float* b_o   = (const float*)d_in[7];
    float* out = (float*)d_out;

    short* ws    = (short*)d_ws;
    short* xn    = ws;                                  // 16384*256
    short* Wuv_t = xn    + (long)16384 * 256;           // 1152*256
    short* Wo_t  = Wuv_t + (long)1152 * 256;            // 256*512
    short* u     = Wo_t  + (long)256 * 512;             // 16384*512
    short* vfrag = u     + (long)16384 * 512;           // 16384*512 (frag layout)
    short* qq    = vfrag + (long)16384 * 512;           // 16384*128
    short* kk    = qq    + (long)16384 * 128;           // 16384*128

    k_pre<<<4512, 256, 0, stream>>>(x, g, xn, Wuv, Wo, Wuv_t, Wo_t);
    k_gemm1<<<dim3(128, 9), 256, 0, stream>>>(xn, Wuv_t, b_uv, gamma, beta,
                                              u, vfrag, qq, kk);
    k_attn<<<256, 512, 67584, stream>>>(qq, kk, vfrag, u, Wo_t, b_o, out);
}